// Round 6
// baseline (120.142 us; speedup 1.0000x reference)
//
#include <hip/hip_runtime.h>
#include <hip/hip_bf16.h>

#define NRED 7

__device__ __forceinline__ float waveReduce(float v) {
#pragma unroll
    for (int o = 32; o > 0; o >>= 1) v += __shfl_down(v, o, 64);
    return v;
}

// Accumulator slots:
// 0: sum(-score[li])      1: count(match!=-1)   2: sum(success&label)
// 3: count(idx!=-1)       4: sum(success&pred)  5: sum(d*d)
// 6: sum over pred of (d2/c + 0.12*log(c))
__global__ __launch_bounds__(256) void setloss_partial(
        const float* __restrict__ scores,
        const float* __restrict__ cov,
        const float* __restrict__ pos,
        const float* __restrict__ pose,
        const int* __restrict__ indices,
        const int* __restrict__ match,
        float* __restrict__ part,
        int N, int grid) {
    float acc[NRED];
#pragma unroll
    for (int k = 0; k < NRED; ++k) acc[k] = 0.0f;

    const int lane = threadIdx.x & 63;
    const int wave = threadIdx.x >> 6;
    // Block covers 1024 consecutive rows; wave covers 256; gather instr k's
    // 64 lanes hit 64 CONSECUTIVE score rows (128B apart -> 8KB contiguous
    // span, sequential DRAM pages) instead of 512B-strided.
    const int wbase = blockIdx.x * 1024 + wave * 256;

    int  r[4];  bool vld[4];
#pragma unroll
    for (int k = 0; k < 4; ++k) { r[k] = wbase + 64 * k + lane; vld[k] = r[k] < N; }

    // Phase 1: match loads (the only dependency of the gathers) — issued first.
    int mt[4];
#pragma unroll
    for (int k = 0; k < 4; ++k) mt[k] = vld[k] ? match[r[k]] : -1;

    // Phase 2: the 4 NT gathers, issued as soon as mt arrives.
    float sc[4];
#pragma unroll
    for (int k = 0; k < 4; ++k) {
        if (vld[k]) {
            const unsigned ur = (unsigned)r[k];
            const unsigned b  = ur / 31u;
            const unsigned i  = ur - b * 31u;
            const int li = (mt[k] < 0) ? 31 : mt[k];
            sc[k] = __builtin_nontemporal_load(
                scores + (size_t)b * 1024u + i * 32u + (unsigned)li);
        } else sc[k] = 0.0f;
    }

    // Phase 3: remaining streams (independent of the gathers, overlap them).
    int oi[4]; float cc[4];
#pragma unroll
    for (int k = 0; k < 4; ++k) oi[k] = vld[k] ? indices[r[k]] : -1;
#pragma unroll
    for (int k = 0; k < 4; ++k) cc[k] = vld[k] ? cov[r[k]] : 1.0f;

    float P[4][3], Q[4][3];
#pragma unroll
    for (int k = 0; k < 4; ++k) {
        const size_t rp = 3 * (size_t)r[k];
        const size_t rq = 7 * (size_t)r[k];
        if (vld[k]) {
            P[k][0] = pos[rp + 0];  P[k][1] = pos[rp + 1];  P[k][2] = pos[rp + 2];
            Q[k][0] = pose[rq + 0]; Q[k][1] = pose[rq + 1]; Q[k][2] = pose[rq + 2];
        } else {
            P[k][0] = P[k][1] = P[k][2] = 0.0f;
            Q[k][0] = Q[k][1] = Q[k][2] = 0.0f;
        }
    }

    // Phase 4: accumulate.
#pragma unroll
    for (int k = 0; k < 4; ++k) {
        if (!vld[k]) continue;
        acc[0] -= sc[k];
        const float succ = (oi[k] == mt[k]) ? 1.0f : 0.0f;
        const bool lv = (mt[k] != -1);
        const bool pv = (oi[k] != -1);
        acc[1] += lv ? 1.0f : 0.0f;
        acc[2] += lv ? succ : 0.0f;
        acc[3] += pv ? 1.0f : 0.0f;
        acc[4] += pv ? succ : 0.0f;
        const float dx = P[k][0] - Q[k][0];
        const float dy = P[k][1] - Q[k][1];
        const float dz = P[k][2] - Q[k][2];
        const float d2 = dx * dx + dy * dy + dz * dz;
        acc[5] += d2;
        if (pv) acc[6] += d2 / cc[k] + 0.12f * logf(cc[k]);
    }

    __shared__ float sdata[NRED][4];
#pragma unroll
    for (int k = 0; k < NRED; ++k) {
        float v = waveReduce(acc[k]);
        if (lane == 0) sdata[k][wave] = v;
    }
    __syncthreads();
    if (threadIdx.x == 0) {
#pragma unroll
        for (int k = 0; k < NRED; ++k)
            part[(size_t)k * grid + blockIdx.x] =
                sdata[k][0] + sdata[k][1] + sdata[k][2] + sdata[k][3];
    }
}

__global__ void setloss_final(const float* __restrict__ part, int grid,
                              float* __restrict__ out, int N) {
    float acc[NRED];
#pragma unroll
    for (int k = 0; k < NRED; ++k) acc[k] = 0.0f;
    for (int t = threadIdx.x; t < grid; t += blockDim.x) {
#pragma unroll
        for (int k = 0; k < NRED; ++k) acc[k] += part[(size_t)k * grid + t];
    }
    __shared__ float sdata[NRED][4];
    const int lane = threadIdx.x & 63;
    const int wave = threadIdx.x >> 6;
#pragma unroll
    for (int k = 0; k < NRED; ++k) {
        float v = waveReduce(acc[k]);
        if (lane == 0) sdata[k][wave] = v;
    }
    __syncthreads();
    if (threadIdx.x == 0) {
        float s[NRED];
#pragma unroll
        for (int k = 0; k < NRED; ++k)
            s[k] = sdata[k][0] + sdata[k][1] + sdata[k][2] + sdata[k][3];

        const float fN = (float)N;
        const float loss_match = s[0] / fN;
        const float loss_pos   = s[5] / fN;     // mean(d*d)*3 == sum/(3N)*3
        const float recall     = (s[1] > 0.0f) ? s[2] / s[1] : 1.0f;
        const float precision  = (s[3] > 0.0f) ? s[4] / s[3] : 1.0f;
        const float loss_cov   = (s[3] > 0.0f) ? s[6] / s[3] : 5.0f;

        out[0] = loss_match + loss_pos + 0.1f * loss_cov;
        out[1] = loss_match;
        out[2] = loss_pos;
        out[3] = 0.0f;
        out[4] = loss_cov;
        out[5] = precision;
        out[6] = recall;
    }
}

extern "C" void kernel_launch(void* const* d_in, const int* in_sizes, int n_in,
                              void* d_out, int out_size, void* d_ws, size_t ws_size,
                              hipStream_t stream) {
    const float* scores  = (const float*)d_in[0];
    const float* cov     = (const float*)d_in[1];
    const float* pos     = (const float*)d_in[2];
    const float* pose    = (const float*)d_in[3];
    const int*   indices = (const int*)d_in[4];
    const int*   match   = (const int*)d_in[5];
    float* out = (float*)d_out;

    const int N = in_sizes[5];            // match is [N,1]

    int grid = (N + 1023) / 1024;         // 1024 consecutive rows per block
    const size_t cap = ws_size / ((size_t)NRED * sizeof(float));
    if ((size_t)grid > cap) grid = (int)cap;
    if (grid < 1) grid = 1;

    float* part = (float*)d_ws;

    setloss_partial<<<grid, 256, 0, stream>>>(scores, cov, pos, pose, indices,
                                              match, part, N, grid);
    setloss_final<<<1, 256, 0, stream>>>(part, grid, out, N);
}

// Round 7
// 113.341 us; speedup vs baseline: 1.0600x; 1.0600x over previous
//
#include <hip/hip_runtime.h>
#include <hip/hip_bf16.h>

#define NRED 7

__device__ __forceinline__ float waveReduce(float v) {
#pragma unroll
    for (int o = 32; o > 0; o >>= 1) v += __shfl_down(v, o, 64);
    return v;
}

// Accumulator slots:
// 0: sum(-score[li])      1: count(match!=-1)   2: sum(success&label)
// 3: count(idx!=-1)       4: sum(success&pred)  5: sum(d*d)
// 6: sum over pred of (d2/c + 0.12*log(c))
//
// Roofline note (R2..R6): the scores gather touches 4.06M distinct 128B
// lines; HBM/fabric moves 128B granules regardless of NT sector masking,
// so gather bus-time ~520MB + dense streams ~211MB = 731MB @ ~6.5TB/s
// ~= 112.5us. This kernel measures ~113.4us -> at the roofline.
__device__ __forceinline__ void rowAcc(int r, int mt, int oi, float c,
                                       float px, float py, float pz,
                                       float qx, float qy, float qz,
                                       const float* __restrict__ scores,
                                       float acc[NRED]) {
    const unsigned ur = (unsigned)r;
    const unsigned b  = ur / 31u;
    const unsigned i  = ur - b * 31u;
    const int li = (mt < 0) ? 31 : mt;
    // NT gather: avoid L2 line allocation; fetch only the needed 64B sector
    const float sc = __builtin_nontemporal_load(
        scores + (size_t)b * 1024u + i * 32u + (unsigned)li);
    acc[0] -= sc;

    const float succ = (oi == mt) ? 1.0f : 0.0f;
    const bool lv = (mt != -1);
    const bool pv = (oi != -1);
    acc[1] += lv ? 1.0f : 0.0f;
    acc[2] += lv ? succ : 0.0f;
    acc[3] += pv ? 1.0f : 0.0f;
    acc[4] += pv ? succ : 0.0f;

    const float dx = px - qx, dy = py - qy, dz = pz - qz;
    const float d2 = dx * dx + dy * dy + dz * dz;
    acc[5] += d2;
    if (pv) acc[6] += d2 / c + 0.12f * logf(c);
}

__global__ __launch_bounds__(256) void setloss_partial(
        const float* __restrict__ scores,
        const float* __restrict__ cov,
        const float* __restrict__ pos,
        const float* __restrict__ pose,
        const int* __restrict__ indices,
        const int* __restrict__ match,
        float* __restrict__ part,
        int N, int grid, int nChunk) {
    float acc[NRED];
#pragma unroll
    for (int k = 0; k < NRED; ++k) acc[k] = 0.0f;

    const int tstride = grid * 256;
    for (int chunk = blockIdx.x * 256 + threadIdx.x; chunk < nChunk; chunk += tstride) {
        const int base = chunk * 4;
        if (base + 3 < N) {
            const int4   mm = *(const int4*)  (match   + base);
            const int4   oo = *(const int4*)  (indices + base);
            const float4 cc = *(const float4*)(cov     + base);
            const float* pp = pos  + 3 * (size_t)base;
            const float4 p0 = *(const float4*)(pp + 0);
            const float4 p1 = *(const float4*)(pp + 4);
            const float4 p2 = *(const float4*)(pp + 8);
            const float* qq = pose + 7 * (size_t)base;
            const float4 q0 = *(const float4*)(qq + 0);   // f0..f3
            const float4 q1 = *(const float4*)(qq + 4);   // f4..f7
            const float4 q2 = *(const float4*)(qq + 8);   // f8..f11
            const float4 q3 = *(const float4*)(qq + 12);  // f12..f15
            const float4 q4 = *(const float4*)(qq + 16);  // f16..f19
            const float4 q5 = *(const float4*)(qq + 20);  // f20..f23

            // row j: pos floats 3j..3j+2 ; pose floats 7j..7j+2
            rowAcc(base + 0, mm.x, oo.x, cc.x, p0.x, p0.y, p0.z, q0.x, q0.y, q0.z, scores, acc);
            rowAcc(base + 1, mm.y, oo.y, cc.y, p0.w, p1.x, p1.y, q1.w, q2.x, q2.y, scores, acc);   // f7,f8,f9
            rowAcc(base + 2, mm.z, oo.z, cc.z, p1.z, p1.w, p2.x, q3.z, q3.w, q4.x, scores, acc);   // f14,f15,f16
            rowAcc(base + 3, mm.w, oo.w, cc.w, p2.y, p2.z, p2.w, q5.y, q5.z, q5.w, scores, acc);   // f21,f22,f23
        } else {
            for (int r = base; r < N; ++r) {
                rowAcc(r, match[r], indices[r], cov[r],
                       pos[3 * (size_t)r + 0], pos[3 * (size_t)r + 1], pos[3 * (size_t)r + 2],
                       pose[7 * (size_t)r + 0], pose[7 * (size_t)r + 1], pose[7 * (size_t)r + 2],
                       scores, acc);
            }
        }
    }

    __shared__ float sdata[NRED][4];
    const int lane = threadIdx.x & 63;
    const int wave = threadIdx.x >> 6;
#pragma unroll
    for (int k = 0; k < NRED; ++k) {
        float v = waveReduce(acc[k]);
        if (lane == 0) sdata[k][wave] = v;
    }
    __syncthreads();
    if (threadIdx.x == 0) {
#pragma unroll
        for (int k = 0; k < NRED; ++k)
            part[(size_t)k * grid + blockIdx.x] =
                sdata[k][0] + sdata[k][1] + sdata[k][2] + sdata[k][3];
    }
}

__global__ void setloss_final(const float* __restrict__ part, int grid,
                              float* __restrict__ out, int N) {
    float acc[NRED];
#pragma unroll
    for (int k = 0; k < NRED; ++k) acc[k] = 0.0f;
    for (int t = threadIdx.x; t < grid; t += blockDim.x) {
#pragma unroll
        for (int k = 0; k < NRED; ++k) acc[k] += part[(size_t)k * grid + t];
    }
    __shared__ float sdata[NRED][4];
    const int lane = threadIdx.x & 63;
    const int wave = threadIdx.x >> 6;
#pragma unroll
    for (int k = 0; k < NRED; ++k) {
        float v = waveReduce(acc[k]);
        if (lane == 0) sdata[k][wave] = v;
    }
    __syncthreads();
    if (threadIdx.x == 0) {
        float s[NRED];
#pragma unroll
        for (int k = 0; k < NRED; ++k)
            s[k] = sdata[k][0] + sdata[k][1] + sdata[k][2] + sdata[k][3];

        const float fN = (float)N;
        const float loss_match = s[0] / fN;
        const float loss_pos   = s[5] / fN;     // mean(d*d)*3 == sum/(3N)*3
        const float recall     = (s[1] > 0.0f) ? s[2] / s[1] : 1.0f;
        const float precision  = (s[3] > 0.0f) ? s[4] / s[3] : 1.0f;
        const float loss_cov   = (s[3] > 0.0f) ? s[6] / s[3] : 5.0f;

        out[0] = loss_match + loss_pos + 0.1f * loss_cov;
        out[1] = loss_match;
        out[2] = loss_pos;
        out[3] = 0.0f;
        out[4] = loss_cov;
        out[5] = precision;
        out[6] = recall;
    }
}

extern "C" void kernel_launch(void* const* d_in, const int* in_sizes, int n_in,
                              void* d_out, int out_size, void* d_ws, size_t ws_size,
                              hipStream_t stream) {
    const float* scores  = (const float*)d_in[0];
    const float* cov     = (const float*)d_in[1];
    const float* pos     = (const float*)d_in[2];
    const float* pose    = (const float*)d_in[3];
    const int*   indices = (const int*)d_in[4];
    const int*   match   = (const int*)d_in[5];
    float* out = (float*)d_out;

    const int N = in_sizes[5];            // match is [N,1]
    const int nChunk = (N + 3) / 4;

    int grid = (nChunk + 255) / 256;      // one 4-row chunk per thread
    const size_t cap = ws_size / ((size_t)NRED * sizeof(float));
    if ((size_t)grid > cap) grid = (int)cap;
    if (grid < 1) grid = 1;

    float* part = (float*)d_ws;

    setloss_partial<<<grid, 256, 0, stream>>>(scores, cov, pos, pose, indices,
                                              match, part, N, grid, nChunk);
    setloss_final<<<1, 256, 0, stream>>>(part, grid, out, N);
}